// Round 5
// baseline (112.516 us; speedup 1.0000x reference)
//
#include <hip/hip_runtime.h>
#include <hip/hip_bf16.h>

#define ATTN_N 8192
#define ATTN_D 128
#define TKEYS 32                      // keys per LDS tile
#define NTILES (ATTN_N / TKEYS)       // 256
#define TILE_ELEMS (TKEYS * ATTN_D)   // 4096 bf16 = 8 KB
#define QROWS 128                     // queries per block (4 waves x 32 rows)
#define SPLITK 8                      // 8-way split-K -> 512 blocks = 2/CU
#define KTPB (NTILES / SPLITK)        // 32 key tiles per block
#define NBUF 4                        // 4-deep LDS ring (T3/T4 counted vmcnt)

typedef __bf16 bf16_t;
typedef bf16_t bf16x2 __attribute__((ext_vector_type(2)));
typedef bf16_t bf16x8 __attribute__((ext_vector_type(8)));
typedef float f32x4 __attribute__((ext_vector_type(4)));

#if __has_builtin(__builtin_amdgcn_exp2f)
#define EXP2(x) __builtin_amdgcn_exp2f(x)
#else
#define EXP2(x) __expf((x) * 0.6931471805599453f)
#endif

// Async global->LDS DMA, 16 B per lane; lane-linear on both sides (m104).
__device__ __forceinline__ void dma16(const bf16_t* g, bf16_t* l) {
  __builtin_amdgcn_global_load_lds(
      (const __attribute__((address_space(1))) void*)g,
      (__attribute__((address_space(3))) void*)l, 16, 0, 0);
}

// ---------------------------------------------------------------------------
// Prep (unchanged from R4, verified): Q -> bf16 linear (scaled by
//   log2(e)/sqrt(128)); K -> key-linear swizzled image; V -> transposed
//   32-key tile image (pairwise key interleave, chunk XOR by (d>>1)&3).
//   grid (N/64, 2) x 256 threads.
// ---------------------------------------------------------------------------
__global__ void prep_kernel(const float* __restrict__ q,
                            const float* __restrict__ k,
                            const float* __restrict__ v,
                            bf16_t* __restrict__ qb,
                            bf16_t* __restrict__ kswz,
                            bf16_t* __restrict__ vtswz) {
  __shared__ bf16_t tile[64][72];
  const int bk = blockIdx.x;      // 64-key block -> two 32-key v-tiles
  const int bd = blockIdx.y;      // 64-d half, 0..1
  const int t = threadIdx.x;      // 0..255
  const float sc = 0.12751744f;   // log2(e) / sqrt(128)

  const int row_l = t >> 2;             // 0..63
  const int key = bk * 64 + row_l;

#pragma unroll
  for (int u = 0; u < 2; ++u) {
    const int j = bd * 8 + (t & 3) * 2 + u;   // d-chunk 0..15
    const float4* qs = (const float4*)(q + (size_t)key * ATTN_D + j * 8);
    const float4* ks = (const float4*)(k + (size_t)key * ATTN_D + j * 8);
    float4 a0 = qs[0], a1 = qs[1];
    float4 b0 = ks[0], b1 = ks[1];
    bf16x8 qo, ko;
    qo[0] = (bf16_t)(a0.x * sc); qo[1] = (bf16_t)(a0.y * sc);
    qo[2] = (bf16_t)(a0.z * sc); qo[3] = (bf16_t)(a0.w * sc);
    qo[4] = (bf16_t)(a1.x * sc); qo[5] = (bf16_t)(a1.y * sc);
    qo[6] = (bf16_t)(a1.z * sc); qo[7] = (bf16_t)(a1.w * sc);
    ko[0] = (bf16_t)b0.x; ko[1] = (bf16_t)b0.y;
    ko[2] = (bf16_t)b0.z; ko[3] = (bf16_t)b0.w;
    ko[4] = (bf16_t)b1.x; ko[5] = (bf16_t)b1.y;
    ko[6] = (bf16_t)b1.z; ko[7] = (bf16_t)b1.w;
    *(bf16x8*)(qb + (size_t)key * ATTN_D + j * 8) = qo;
    *(bf16x8*)(kswz + (size_t)key * ATTN_D + ((j ^ (key & 15)) * 8)) = ko;
  }

  {
    const float* src = v + (size_t)key * ATTN_D + bd * 64 + (t & 3) * 16;
#pragma unroll
    for (int u = 0; u < 4; ++u) {
      float4 a = ((const float4*)src)[u];
      tile[row_l][(t & 3) * 16 + u * 4 + 0] = (bf16_t)a.x;
      tile[row_l][(t & 3) * 16 + u * 4 + 1] = (bf16_t)a.y;
      tile[row_l][(t & 3) * 16 + u * 4 + 2] = (bf16_t)a.z;
      tile[row_l][(t & 3) * 16 + u * 4 + 3] = (bf16_t)a.w;
    }
  }
  __syncthreads();
  {
    const int d_l = t >> 2;            // 0..63
    const int d = bd * 64 + d_l;
    const int cq = t & 3;              // chunk 0..3
#pragma unroll
    for (int h = 0; h < 2; ++h) {      // two 32-key v-tiles in this block
      bf16x8 o;
#pragma unroll
      for (int j = 0; j < 8; ++j) {
        const int kl_ = h * 32 + cq * 4 + (j >> 1) + 16 * (j & 1);
        o[j] = tile[kl_][d_l];
      }
      *(bf16x8*)(vtswz + (size_t)(2 * bk + h) * TILE_ELEMS + d * TKEYS +
                 ((cq ^ ((d >> 1) & 3)) * 8)) = o;
    }
  }
}

// ---------------------------------------------------------------------------
// Flash attention, 128 queries/block x 8-way split-K, counted-vmcnt pipeline,
// 32 rows/wave (2 m-subtiles SHARING each K/V fragment read).
//   R4 post-mortem: LDS port was saturated (16 waves x ~17 b128/iter ~= 3650
//   cyc/CU-iter vs 3540 measured wall). Fix: halve LDS reads per MFMA by
//   having each wave own 32 rows; K/V frags feed 2 MFMAs each (verified R0
//   fragment structure). 4 waves x 256 thr, grid 512, LDS 74 KB -> 2
//   blocks/CU (2 independent barrier groups; waves halve but they were
//   redundant LDS readers, not useful latency hiders).
//   4-deep ring, counted vmcnt: 4 dma/thread/tile-pair -> steady-state wait
//   vmcnt(8) (tiles it+2/it+3 in flight), NEVER 0 until tail (T4).
// MFMA layouts (mfma_f32_16x16x32_bf16, verified gfx950):
//   A: m = lane&15, k = (lane>>4)*8 + j
//   B: n = lane&15, k = (lane>>4)*8 + j
//   C/D: col = lane&15, row = (lane>>4)*4 + reg
// ---------------------------------------------------------------------------
__global__ __launch_bounds__(256, 4) void flash_attn_kernel(
    const bf16_t* __restrict__ qb, const bf16_t* __restrict__ kswz,
    const bf16_t* __restrict__ vtswz, float* __restrict__ partO,
    float* __restrict__ partL) {
  __shared__ __align__(16) bf16_t KV[NBUF][2][TILE_ELEMS];  // 64 KB ring
  __shared__ __align__(16) bf16_t Ps[4][32][40];            // 10 KB

  const int t = threadIdx.x;
  const int w = t >> 6;          // 0..3 = 32-row subtile
  const int lane = t & 63;
  const int quad = lane >> 4;
  const int col = lane & 15;
  const int blk = blockIdx.x;
  const int qg = blk >> 3;       // 0..63
  const int kh = blk & 7;        // key eighth == XCD
  const int q0 = qg * QROWS;
  const int ktbase = kh * KTPB;
  const int stg = ((blk >> 3) & 3) * 8;   // stagger: decorrelate L2 streams

  // Swizzled LDS offsets (row*stride + (chunk^swz)*8).
  int offK[4][2], offV[8];
#pragma unroll
  for (int c = 0; c < 4; ++c)
#pragma unroll
    for (int ni = 0; ni < 2; ++ni)
      offK[c][ni] = (ni * 16 + col) * ATTN_D + (((c * 4 + quad) ^ col) * 8);
#pragma unroll
  for (int ds = 0; ds < 8; ++ds)
    offV[ds] = (ds * 16 + col) * TKEYS + ((quad ^ ((col >> 1) & 3)) * 8);

  // Q fragments: 2 row-subtiles x 4 k-chunks, registers for whole kernel.
  bf16x8 aq[2][4];
#pragma unroll
  for (int mi = 0; mi < 2; ++mi) {
    const int row = q0 + w * 32 + mi * 16 + col;
#pragma unroll
    for (int c = 0; c < 4; ++c)
      aq[mi][c] = *(const bf16x8*)(qb + (size_t)row * ATTN_D + c * 32 + quad * 8);
  }

  f32x4 oacc[2][8];
#pragma unroll
  for (int mi = 0; mi < 2; ++mi)
#pragma unroll
    for (int i = 0; i < 8; ++i) oacc[mi][i] = (f32x4){0.f, 0.f, 0.f, 0.f};
  float l_part[2][4] = {{0.f, 0.f, 0.f, 0.f}, {0.f, 0.f, 0.f, 0.f}};

  // Prologue: tiles 0..2 into bufs 0..2 (2 K-dma + 2 V-dma per thread each).
#pragma unroll
  for (int pt = 0; pt < 3; ++pt) {
    const int kt = ktbase + ((stg + pt) & (KTPB - 1));
#pragma unroll
    for (int u = 0; u < 2; ++u) {
      dma16(kswz + (size_t)kt * TILE_ELEMS + t * 8 + u * 2048,
            &KV[pt][0][t * 8 + u * 2048]);
      dma16(vtswz + (size_t)kt * TILE_ELEMS + t * 8 + u * 2048,
            &KV[pt][1][t * 8 + u * 2048]);
    }
  }
  asm volatile("s_waitcnt vmcnt(8)" ::: "memory");  // tile 0 landed; 1,2 fly
  __builtin_amdgcn_s_barrier();

  for (int it = 0; it < KTPB; ++it) {
    const int buf = it & (NBUF - 1);
    if (it + 3 < KTPB) {
      const int nt = ktbase + ((stg + it + 3) & (KTPB - 1));
      const int nb = (it + 3) & (NBUF - 1);
#pragma unroll
      for (int u = 0; u < 2; ++u) {
        dma16(kswz + (size_t)nt * TILE_ELEMS + t * 8 + u * 2048,
              &KV[nb][0][t * 8 + u * 2048]);
        dma16(vtswz + (size_t)nt * TILE_ELEMS + t * 8 + u * 2048,
              &KV[nb][1][t * 8 + u * 2048]);
      }
    }
    const bf16_t* Kb = KV[buf][0];
    const bf16_t* Vb = KV[buf][1];

    // --- S = Q K^T: 2 m-subtiles x 2 n-subtiles, K frags shared across mi.
    f32x4 s[2][2];
#pragma unroll
    for (int mi = 0; mi < 2; ++mi)
#pragma unroll
      for (int ni = 0; ni < 2; ++ni) s[mi][ni] = (f32x4){0.f, 0.f, 0.f, 0.f};
    __builtin_amdgcn_s_setprio(1);
#pragma unroll
    for (int c = 0; c < 4; ++c) {
      bf16x8 b0 = *(const bf16x8*)(Kb + offK[c][0]);
      bf16x8 b1 = *(const bf16x8*)(Kb + offK[c][1]);
      s[0][0] = __builtin_amdgcn_mfma_f32_16x16x32_bf16(aq[0][c], b0, s[0][0], 0, 0, 0);
      s[1][0] = __builtin_amdgcn_mfma_f32_16x16x32_bf16(aq[1][c], b0, s[1][0], 0, 0, 0);
      s[0][1] = __builtin_amdgcn_mfma_f32_16x16x32_bf16(aq[0][c], b1, s[0][1], 0, 0, 0);
      s[1][1] = __builtin_amdgcn_mfma_f32_16x16x32_bf16(aq[1][c], b1, s[1][1], 0, 0, 0);
    }
    __builtin_amdgcn_s_setprio(0);

    // --- p = 2^s; lane-local denominator; packed pair-store (key i <-> pos
    //     2i, key i+16 <-> pos 2i+1).
#pragma unroll
    for (int mi = 0; mi < 2; ++mi)
#pragma unroll
      for (int r = 0; r < 4; ++r) {
        float p0 = EXP2(s[mi][0][r]);
        float p1 = EXP2(s[mi][1][r]);
        l_part[mi][r] += p0 + p1;
        *(bf16x2*)&Ps[w][mi * 16 + quad * 4 + r][col * 2] =
            (bf16x2){(bf16_t)p0, (bf16_t)p1};
      }

    // --- O += P V: V frags shared across the 2 m-subtiles.
    bf16x8 ap0 = *(const bf16x8*)&Ps[w][col][quad * 8];
    bf16x8 ap1 = *(const bf16x8*)&Ps[w][16 + col][quad * 8];
    __builtin_amdgcn_s_setprio(1);
#pragma unroll
    for (int ds = 0; ds < 8; ++ds) {
      bf16x8 bv = *(const bf16x8*)(Vb + offV[ds]);
      oacc[0][ds] = __builtin_amdgcn_mfma_f32_16x16x32_bf16(ap0, bv, oacc[0][ds], 0, 0, 0);
      oacc[1][ds] = __builtin_amdgcn_mfma_f32_16x16x32_bf16(ap1, bv, oacc[1][ds], 0, 0, 0);
    }
    __builtin_amdgcn_s_setprio(0);

    // --- counted wait: tile it+1 landed; tiles it+2/it+3 (8 dma ops) stay
    //     in flight across the barrier (T4). Tail iters drain what's left.
    if (it + 3 < KTPB) {
      asm volatile("s_waitcnt vmcnt(8)" ::: "memory");
      __builtin_amdgcn_s_barrier();
    } else if (it + 2 < KTPB) {
      asm volatile("s_waitcnt vmcnt(4)" ::: "memory");
      __builtin_amdgcn_s_barrier();
    } else if (it + 1 < KTPB) {
      asm volatile("s_waitcnt vmcnt(0)" ::: "memory");
      __builtin_amdgcn_s_barrier();
    }
  }

  // --- epilogue: partial L (reduce over the 16 col-lanes of each quad row).
#pragma unroll
  for (int mi = 0; mi < 2; ++mi)
#pragma unroll
    for (int r = 0; r < 4; ++r) {
      float v = l_part[mi][r];
#pragma unroll
      for (int off = 1; off < 16; off <<= 1)
        v += __shfl_xor(v, off, 64);
      if (col == 0)
        partL[(size_t)blk * QROWS + w * 32 + mi * 16 + quad * 4 + r] = v;
    }

  // --- direct store of this wave's 32 unnormalized O rows (no LDS merge).
  {
    float* dst = partO + ((size_t)blk * QROWS + w * 32) * ATTN_D;
#pragma unroll
    for (int mi = 0; mi < 2; ++mi)
#pragma unroll
      for (int ds = 0; ds < 8; ++ds)
#pragma unroll
        for (int r = 0; r < 4; ++r)
          dst[(mi * 16 + quad * 4 + r) * ATTN_D + ds * 16 + col] = oacc[mi][ds][r];
  }
}

// ---------------------------------------------------------------------------
// Merge: out[row] = (sum of 8 split-K partial O) / (sum of 8 partial L).
//   1024 blocks x 256 threads, one float4 per thread.
// ---------------------------------------------------------------------------
__global__ void merge_kernel(const float* __restrict__ partO,
                             const float* __restrict__ partL,
                             float* __restrict__ out) {
  const int idx = blockIdx.x * blockDim.x + threadIdx.x;  // float4 index
  const int row = idx >> 5;          // 32 float4 per 128-elem row
  const int gi = row >> 7;           // query group 0..63
  const int rl = row & 127;
  const int li = rl * 32 + (idx & 31);
  float L = 0.f;
  float4 acc = {0.f, 0.f, 0.f, 0.f};
#pragma unroll
  for (int i = 0; i < 8; ++i) {
    const size_t b = (size_t)(8 * gi + i);
    L += partL[b * QROWS + rl];
    float4 a = ((const float4*)(partO + b * (QROWS * ATTN_D)))[li];
    acc.x += a.x; acc.y += a.y; acc.z += a.z; acc.w += a.w;
  }
  const float invL = 1.0f / L;
  float4 o;
  o.x = acc.x * invL; o.y = acc.y * invL;
  o.z = acc.z * invL; o.w = acc.w * invL;
  ((float4*)out)[idx] = o;
}

// ---------------------------------------------------------------------------
extern "C" void kernel_launch(void* const* d_in, const int* in_sizes, int n_in,
                              void* d_out, int out_size, void* d_ws, size_t ws_size,
                              hipStream_t stream) {
  const float* q = (const float*)d_in[0];
  const float* k = (const float*)d_in[1];
  const float* v = (const float*)d_in[2];
  float* out = (float*)d_out;

  // Workspace: qb | kswz | vtswz (bf16, 2 MB each) | partO 33.6 MB | partL 256 KB.
  bf16_t* qb = (bf16_t*)d_ws;
  bf16_t* kswz = qb + (size_t)ATTN_N * ATTN_D;
  bf16_t* vtswz = kswz + (size_t)ATTN_N * ATTN_D;
  float* partO = (float*)(vtswz + (size_t)ATTN_N * ATTN_D);
  float* partL = partO + (size_t)512 * QROWS * ATTN_D;

  prep_kernel<<<dim3(ATTN_N / 64, 2), 256, 0, stream>>>(q, k, v, qb, kswz, vtswz);
  flash_attn_kernel<<<512, 256, 0, stream>>>(qb, kswz, vtswz, partO, partL);
  merge_kernel<<<(ATTN_N * ATTN_D / 4) / 256, 256, 0, stream>>>(partO, partL, out);
}

// Round 6
// 105.224 us; speedup vs baseline: 1.0693x; 1.0693x over previous
//
#include <hip/hip_runtime.h>
#include <hip/hip_bf16.h>

#define ATTN_N 8192
#define ATTN_D 128
#define TKEYS 32                      // keys per LDS tile
#define NTILES (ATTN_N / TKEYS)       // 256
#define TILE_ELEMS (TKEYS * ATTN_D)   // 4096 bf16 = 8 KB
#define QROWS 128                     // queries per block (4 waves x 32 rows)
#define SPLITK 8                      // 8-way split-K -> 512 blocks = 2/CU
#define KTPB (NTILES / SPLITK)        // 32 key tiles per block
#define NBUF 4                        // 4-deep LDS ring (T3/T4 counted vmcnt)

typedef __bf16 bf16_t;
typedef bf16_t bf16x8 __attribute__((ext_vector_type(8)));
typedef float f32x4 __attribute__((ext_vector_type(4)));

#if __has_builtin(__builtin_amdgcn_exp2f)
#define EXP2(x) __builtin_amdgcn_exp2f(x)
#else
#define EXP2(x) __expf((x) * 0.6931471805599453f)
#endif

// Async global->LDS DMA, 16 B per lane; lane-linear on both sides (m104).
__device__ __forceinline__ void dma16(const bf16_t* g, bf16_t* l) {
  __builtin_amdgcn_global_load_lds(
      (const __attribute__((address_space(1))) void*)g,
      (__attribute__((address_space(3))) void*)l, 16, 0, 0);
}

// ---------------------------------------------------------------------------
// Prep: Q -> bf16 linear (scaled by log2(e)/sqrt(128), so flash uses exp2);
//       K -> bf16 key-linear swizzled image (16B chunk j at j ^ (key&15));
//       V -> bf16 transposed 32-key tile image vtswz: tile = key/32 is
//            [d=0..127][key-slot=0..31]; key-slot s holds phys key
//            (s&4 ? 16 + 4*(s>>3) + (s&3) : 4*(s>>3) + (s&3)) -- the
//            quad-block interleave matching the SWAPPED-QK register P
//            layout (lane quad holds keys {4q..4q+3} u {16+4q..16+4q+3});
//            16B chunks XOR'd by (d>>1)&3 for bank spread.
//   grid (N/64, 2) x 256 threads.
// ---------------------------------------------------------------------------
__global__ void prep_kernel(const float* __restrict__ q,
                            const float* __restrict__ k,
                            const float* __restrict__ v,
                            bf16_t* __restrict__ qb,
                            bf16_t* __restrict__ kswz,
                            bf16_t* __restrict__ vtswz) {
  __shared__ bf16_t tile[64][72];
  const int bk = blockIdx.x;      // 64-key block -> two 32-key v-tiles
  const int bd = blockIdx.y;      // 64-d half, 0..1
  const int t = threadIdx.x;      // 0..255
  const float sc = 0.12751744f;   // log2(e) / sqrt(128)

  const int row_l = t >> 2;             // 0..63
  const int key = bk * 64 + row_l;

#pragma unroll
  for (int u = 0; u < 2; ++u) {
    const int j = bd * 8 + (t & 3) * 2 + u;   // d-chunk 0..15
    const float4* qs = (const float4*)(q + (size_t)key * ATTN_D + j * 8);
    const float4* ks = (const float4*)(k + (size_t)key * ATTN_D + j * 8);
    float4 a0 = qs[0], a1 = qs[1];
    float4 b0 = ks[0], b1 = ks[1];
    bf16x8 qo, ko;
    qo[0] = (bf16_t)(a0.x * sc); qo[1] = (bf16_t)(a0.y * sc);
    qo[2] = (bf16_t)(a0.z * sc); qo[3] = (bf16_t)(a0.w * sc);
    qo[4] = (bf16_t)(a1.x * sc); qo[5] = (bf16_t)(a1.y * sc);
    qo[6] = (bf16_t)(a1.z * sc); qo[7] = (bf16_t)(a1.w * sc);
    ko[0] = (bf16_t)b0.x; ko[1] = (bf16_t)b0.y;
    ko[2] = (bf16_t)b0.z; ko[3] = (bf16_t)b0.w;
    ko[4] = (bf16_t)b1.x; ko[5] = (bf16_t)b1.y;
    ko[6] = (bf16_t)b1.z; ko[7] = (bf16_t)b1.w;
    *(bf16x8*)(qb + (size_t)key * ATTN_D + j * 8) = qo;
    *(bf16x8*)(kswz + (size_t)key * ATTN_D + ((j ^ (key & 15)) * 8)) = ko;
  }

  {
    const float* src = v + (size_t)key * ATTN_D + bd * 64 + (t & 3) * 16;
#pragma unroll
    for (int u = 0; u < 4; ++u) {
      float4 a = ((const float4*)src)[u];
      tile[row_l][(t & 3) * 16 + u * 4 + 0] = (bf16_t)a.x;
      tile[row_l][(t & 3) * 16 + u * 4 + 1] = (bf16_t)a.y;
      tile[row_l][(t & 3) * 16 + u * 4 + 2] = (bf16_t)a.z;
      tile[row_l][(t & 3) * 16 + u * 4 + 3] = (bf16_t)a.w;
    }
  }
  __syncthreads();
  {
    const int d_l = t >> 2;            // 0..63
    const int d = bd * 64 + d_l;
    const int cq = t & 3;              // chunk 0..3 (key-slots 8cq..8cq+7)
#pragma unroll
    for (int h = 0; h < 2; ++h) {      // two 32-key v-tiles in this block
      bf16x8 o;
#pragma unroll
      for (int j = 0; j < 8; ++j) {
        // slot 8cq+j -> phys key: quad-block interleave for swapped-QK P.
        const int kl_ = h * 32 + ((j & 4) << 2) + 4 * cq + (j & 3);
        o[j] = tile[kl_][d_l];
      }
      *(bf16x8*)(vtswz + (size_t)(2 * bk + h) * TILE_ELEMS + d * TKEYS +
                 ((cq ^ ((d >> 1) & 3)) * 8)) = o;
    }
  }
}

// ---------------------------------------------------------------------------
// Flash attention, 128 queries/block x 8-way split-K, counted-vmcnt pipeline,
// SWAPPED-QK register-resident softmax (no P LDS round-trip).
//   R5 post-mortem: wall pinned at ~3700 cyc/iter by the serial chain
//   QK -> exp2 -> Ps-write -> lgkm -> Ps-read -> PV x barrier convoy, not by
//   any throughput pipe. Fix: compute S = mfma(A=K, B=Q); then lane holds
//   S[key=quad*4+r (+16)][q=col] -- exactly the PV A-frag layout
//   (m=lane&15=q, k=quad*8+j) given the V image's quad-block key order.
//   P: exp2 + bf16-pack in registers, straight into PV. No Ps buffer.
//   4 waves x 256 thr, grid 512, LDS 64 KB -> 2 blocks/CU (2 independent
//   barrier groups). 4-deep ring, steady-state wait vmcnt(8): 2 tile-pairs
//   in flight across the barrier, never drain to 0 until tail (T4).
// MFMA layouts (mfma_f32_16x16x32_bf16, verified gfx950):
//   A: m = lane&15, k = (lane>>4)*8 + j
//   B: n = lane&15, k = (lane>>4)*8 + j
//   C/D: n = lane&15 (col), m = (lane>>4)*4 + reg
// ---------------------------------------------------------------------------
__global__ __launch_bounds__(256, 2) void flash_attn_kernel(
    const bf16_t* __restrict__ qb, const bf16_t* __restrict__ kswz,
    const bf16_t* __restrict__ vtswz, float* __restrict__ partO,
    float* __restrict__ partL) {
  __shared__ __align__(16) bf16_t KV[NBUF][2][TILE_ELEMS];  // 64 KB ring

  const int t = threadIdx.x;
  const int w = t >> 6;          // 0..3 = 32-row q subtile
  const int lane = t & 63;
  const int quad = lane >> 4;
  const int col = lane & 15;
  const int blk = blockIdx.x;
  const int qg = blk >> 3;       // 0..63
  const int kh = blk & 7;        // key eighth == XCD
  const int q0 = qg * QROWS;
  const int ktbase = kh * KTPB;
  const int stg = ((blk >> 3) & 3) * 8;   // stagger: decorrelate L2 streams

  // Swizzled LDS offsets (row*stride + (chunk^swz)*8).
  int offK[4][2], offV[8];
#pragma unroll
  for (int c = 0; c < 4; ++c)
#pragma unroll
    for (int ks = 0; ks < 2; ++ks)
      offK[c][ks] = (ks * 16 + col) * ATTN_D + (((c * 4 + quad) ^ col) * 8);
#pragma unroll
  for (int ds = 0; ds < 8; ++ds)
    offV[ds] = (ds * 16 + col) * TKEYS + ((quad ^ ((col >> 1) & 3)) * 8);

  // Q fragments (B operand): 2 q-subtiles x 4 k-chunks, in regs all kernel.
  bf16x8 aq[2][4];
#pragma unroll
  for (int qs = 0; qs < 2; ++qs) {
    const int row = q0 + w * 32 + qs * 16 + col;
#pragma unroll
    for (int c = 0; c < 4; ++c)
      aq[qs][c] = *(const bf16x8*)(qb + (size_t)row * ATTN_D + c * 32 + quad * 8);
  }

  f32x4 oacc[2][8];
#pragma unroll
  for (int qs = 0; qs < 2; ++qs)
#pragma unroll
    for (int i = 0; i < 8; ++i) oacc[qs][i] = (f32x4){0.f, 0.f, 0.f, 0.f};
  float l_part[2] = {0.f, 0.f};

  // Prologue: tiles 0..2 into bufs 0..2 (2 K-dma + 2 V-dma per thread each).
#pragma unroll
  for (int pt = 0; pt < 3; ++pt) {
    const int kt = ktbase + ((stg + pt) & (KTPB - 1));
#pragma unroll
    for (int u = 0; u < 2; ++u) {
      dma16(kswz + (size_t)kt * TILE_ELEMS + t * 8 + u * 2048,
            &KV[pt][0][t * 8 + u * 2048]);
      dma16(vtswz + (size_t)kt * TILE_ELEMS + t * 8 + u * 2048,
            &KV[pt][1][t * 8 + u * 2048]);
    }
  }
  asm volatile("s_waitcnt vmcnt(8)" ::: "memory");  // tile 0 landed; 1,2 fly
  __builtin_amdgcn_s_barrier();

  for (int it = 0; it < KTPB; ++it) {
    const int buf = it & (NBUF - 1);
    if (it + 3 < KTPB) {
      const int nt = ktbase + ((stg + it + 3) & (KTPB - 1));
      const int nb = (it + 3) & (NBUF - 1);
#pragma unroll
      for (int u = 0; u < 2; ++u) {
        dma16(kswz + (size_t)nt * TILE_ELEMS + t * 8 + u * 2048,
              &KV[nb][0][t * 8 + u * 2048]);
        dma16(vtswz + (size_t)nt * TILE_ELEMS + t * 8 + u * 2048,
              &KV[nb][1][t * 8 + u * 2048]);
      }
    }
    const bf16_t* Kb = KV[buf][0];
    const bf16_t* Vb = KV[buf][1];

    // --- S = K Q^T (swapped): s[ksub][qsub]; lane: q=col, key=quad*4+r.
    f32x4 s[2][2];
#pragma unroll
    for (int ks = 0; ks < 2; ++ks)
#pragma unroll
      for (int qs = 0; qs < 2; ++qs) s[ks][qs] = (f32x4){0.f, 0.f, 0.f, 0.f};
    __builtin_amdgcn_s_setprio(1);
#pragma unroll
    for (int c = 0; c < 4; ++c) {
      bf16x8 k0 = *(const bf16x8*)(Kb + offK[c][0]);
      bf16x8 k1 = *(const bf16x8*)(Kb + offK[c][1]);
      s[0][0] = __builtin_amdgcn_mfma_f32_16x16x32_bf16(k0, aq[0][c], s[0][0], 0, 0, 0);
      s[0][1] = __builtin_amdgcn_mfma_f32_16x16x32_bf16(k0, aq[1][c], s[0][1], 0, 0, 0);
      s[1][0] = __builtin_amdgcn_mfma_f32_16x16x32_bf16(k1, aq[0][c], s[1][0], 0, 0, 0);
      s[1][1] = __builtin_amdgcn_mfma_f32_16x16x32_bf16(k1, aq[1][c], s[1][1], 0, 0, 0);
    }
    __builtin_amdgcn_s_setprio(0);

    // --- p = 2^s, packed to the PV A-frag IN REGISTERS (k = quad*8+j:
    //     j<4 -> ksub0 (phys 4*quad+j), j>=4 -> ksub1 (phys 16+4*quad+j-4);
    //     V image uses the same quad-block key order).
    bf16x8 ap[2];
#pragma unroll
    for (int qs = 0; qs < 2; ++qs) {
      float pa0 = EXP2(s[0][qs][0]), pa1 = EXP2(s[0][qs][1]);
      float pa2 = EXP2(s[0][qs][2]), pa3 = EXP2(s[0][qs][3]);
      float pb0 = EXP2(s[1][qs][0]), pb1 = EXP2(s[1][qs][1]);
      float pb2 = EXP2(s[1][qs][2]), pb3 = EXP2(s[1][qs][3]);
      l_part[qs] += (pa0 + pa1 + pa2 + pa3) + (pb0 + pb1 + pb2 + pb3);
      ap[qs][0] = (bf16_t)pa0; ap[qs][1] = (bf16_t)pa1;
      ap[qs][2] = (bf16_t)pa2; ap[qs][3] = (bf16_t)pa3;
      ap[qs][4] = (bf16_t)pb0; ap[qs][5] = (bf16_t)pb1;
      ap[qs][6] = (bf16_t)pb2; ap[qs][7] = (bf16_t)pb3;
    }

    // --- O += P V: V frags shared across the 2 q-subtiles.
    __builtin_amdgcn_s_setprio(1);
#pragma unroll
    for (int ds = 0; ds < 8; ++ds) {
      bf16x8 bv = *(const bf16x8*)(Vb + offV[ds]);
      oacc[0][ds] = __builtin_amdgcn_mfma_f32_16x16x32_bf16(ap[0], bv, oacc[0][ds], 0, 0, 0);
      oacc[1][ds] = __builtin_amdgcn_mfma_f32_16x16x32_bf16(ap[1], bv, oacc[1][ds], 0, 0, 0);
    }
    __builtin_amdgcn_s_setprio(0);

    // --- counted wait: tile it+1 landed; tiles it+2/it+3 (8 dma ops) stay
    //     in flight across the barrier (T4). Tail iters drain what's left.
    if (it + 3 < KTPB) {
      asm volatile("s_waitcnt vmcnt(8)" ::: "memory");
      __builtin_amdgcn_s_barrier();
    } else if (it + 2 < KTPB) {
      asm volatile("s_waitcnt vmcnt(4)" ::: "memory");
      __builtin_amdgcn_s_barrier();
    } else if (it + 1 < KTPB) {
      asm volatile("s_waitcnt vmcnt(0)" ::: "memory");
      __builtin_amdgcn_s_barrier();
    }
  }

  // --- epilogue: partial L. Lane holds the sum over its 8 keys for q=col;
  //     total over the 32-key tiles = reduce across the 4 quads.
#pragma unroll
  for (int qs = 0; qs < 2; ++qs) {
    float v = l_part[qs];
    v += __shfl_xor(v, 16, 64);
    v += __shfl_xor(v, 32, 64);
    if (quad == 0)
      partL[(size_t)blk * QROWS + w * 32 + qs * 16 + col] = v;
  }

  // --- direct store of this wave's 32 unnormalized O rows.
  {
    float* dst = partO + ((size_t)blk * QROWS + w * 32) * ATTN_D;
#pragma unroll
    for (int qs = 0; qs < 2; ++qs)
#pragma unroll
      for (int ds = 0; ds < 8; ++ds)
#pragma unroll
        for (int r = 0; r < 4; ++r)
          dst[(qs * 16 + quad * 4 + r) * ATTN_D + ds * 16 + col] = oacc[qs][ds][r];
  }
}

// ---------------------------------------------------------------------------
// Merge: out[row] = (sum of 8 split-K partial O) / (sum of 8 partial L).
//   1024 blocks x 256 threads, one float4 per thread.
// ---------------------------------------------------------------------------
__global__ void merge_kernel(const float* __restrict__ partO,
                             const float* __restrict__ partL,
                             float* __restrict__ out) {
  const int idx = blockIdx.x * blockDim.x + threadIdx.x;  // float4 index
  const int row = idx >> 5;          // 32 float4 per 128-elem row
  const int gi = row >> 7;           // query group 0..63
  const int rl = row & 127;
  const int li = rl * 32 + (idx & 31);
  float L = 0.f;
  float4 acc = {0.f, 0.f, 0.f, 0.f};
#pragma unroll
  for (int i = 0; i < 8; ++i) {
    const size_t b = (size_t)(8 * gi + i);
    L += partL[b * QROWS + rl];
    float4 a = ((const float4*)(partO + b * (QROWS * ATTN_D)))[li];
    acc.x += a.x; acc.y += a.y; acc.z += a.z; acc.w += a.w;
  }
  const float invL = 1.0f / L;
  float4 o;
  o.x = acc.x * invL; o.y = acc.y * invL;
  o.z = acc.z * invL; o.w = acc.w * invL;
  ((float4*)out)[idx] = o;
}

// ---------------------------------------------------------------------------
extern "C" void kernel_launch(void* const* d_in, const int* in_sizes, int n_in,
                              void* d_out, int out_size, void* d_ws, size_t ws_size,
                              hipStream_t stream) {
  const float* q = (const float*)d_in[0];
  const float* k = (const float*)d_in[1];
  const float* v = (const float*)d_in[2];
  float* out = (float*)d_out;

  // Workspace: qb | kswz | vtswz (bf16, 2 MB each) | partO 33.6 MB | partL 256 KB.
  bf16_t* qb = (bf16_t*)d_ws;
  bf16_t* kswz = qb + (size_t)ATTN_N * ATTN_D;
  bf16_t* vtswz = kswz + (size_t)ATTN_N * ATTN_D;
  float* partO = (float*)(vtswz + (size_t)ATTN_N * ATTN_D);
  float* partL = partO + (size_t)512 * QROWS * ATTN_D;

  prep_kernel<<<dim3(ATTN_N / 64, 2), 256, 0, stream>>>(q, k, v, qb, kswz, vtswz);
  flash_attn_kernel<<<512, 256, 0, stream>>>(qb, kswz, vtswz, partO, partL);
  merge_kernel<<<(ATTN_N * ATTN_D / 4) / 256, 256, 0, stream>>>(partO, partL, out);
}

// Round 7
// 104.109 us; speedup vs baseline: 1.0808x; 1.0107x over previous
//
#include <hip/hip_runtime.h>
#include <hip/hip_bf16.h>

#define ATTN_N 8192
#define ATTN_D 128
#define TKEYS 32                      // keys per LDS tile
#define NTILES (ATTN_N / TKEYS)       // 256
#define TILE_ELEMS (TKEYS * ATTN_D)   // 4096 bf16 = 8 KB
#define QROWS 128                     // queries per block (4 waves x 32 rows)
#define SPLITK 8                      // 8-way split-K -> 512 blocks = 2/CU
#define KTPB (NTILES / SPLITK)        // 32 key tiles per block
#define NBUF 4                        // 4-deep LDS ring (T3/T4 counted vmcnt)

typedef __bf16 bf16_t;
typedef bf16_t bf16x8 __attribute__((ext_vector_type(8)));
typedef float f32x4 __attribute__((ext_vector_type(4)));

#if __has_builtin(__builtin_amdgcn_exp2f)
#define EXP2(x) __builtin_amdgcn_exp2f(x)
#else
#define EXP2(x) __expf((x) * 0.6931471805599453f)
#endif

// Async global->LDS DMA, 16 B per lane; lane-linear on both sides (m104).
__device__ __forceinline__ void dma16(const bf16_t* g, bf16_t* l) {
  __builtin_amdgcn_global_load_lds(
      (const __attribute__((address_space(1))) void*)g,
      (__attribute__((address_space(3))) void*)l, 16, 0, 0);
}

// ---------------------------------------------------------------------------
// Prep (unchanged from R6, verified): Q -> bf16 linear (scaled by
//   log2(e)/sqrt(128)); K -> key-linear swizzled image (chunk j at
//   j ^ (key&15)); V -> transposed 32-key tile image, key-slot quad-block
//   interleave matching the swapped-QK register P layout, chunks XOR'd by
//   (d>>1)&3.  grid (N/64, 2) x 256 threads.
// ---------------------------------------------------------------------------
__global__ void prep_kernel(const float* __restrict__ q,
                            const float* __restrict__ k,
                            const float* __restrict__ v,
                            bf16_t* __restrict__ qb,
                            bf16_t* __restrict__ kswz,
                            bf16_t* __restrict__ vtswz) {
  __shared__ bf16_t tile[64][72];
  const int bk = blockIdx.x;      // 64-key block -> two 32-key v-tiles
  const int bd = blockIdx.y;      // 64-d half, 0..1
  const int t = threadIdx.x;      // 0..255
  const float sc = 0.12751744f;   // log2(e) / sqrt(128)

  const int row_l = t >> 2;             // 0..63
  const int key = bk * 64 + row_l;

#pragma unroll
  for (int u = 0; u < 2; ++u) {
    const int j = bd * 8 + (t & 3) * 2 + u;   // d-chunk 0..15
    const float4* qs = (const float4*)(q + (size_t)key * ATTN_D + j * 8);
    const float4* ks = (const float4*)(k + (size_t)key * ATTN_D + j * 8);
    float4 a0 = qs[0], a1 = qs[1];
    float4 b0 = ks[0], b1 = ks[1];
    bf16x8 qo, ko;
    qo[0] = (bf16_t)(a0.x * sc); qo[1] = (bf16_t)(a0.y * sc);
    qo[2] = (bf16_t)(a0.z * sc); qo[3] = (bf16_t)(a0.w * sc);
    qo[4] = (bf16_t)(a1.x * sc); qo[5] = (bf16_t)(a1.y * sc);
    qo[6] = (bf16_t)(a1.z * sc); qo[7] = (bf16_t)(a1.w * sc);
    ko[0] = (bf16_t)b0.x; ko[1] = (bf16_t)b0.y;
    ko[2] = (bf16_t)b0.z; ko[3] = (bf16_t)b0.w;
    ko[4] = (bf16_t)b1.x; ko[5] = (bf16_t)b1.y;
    ko[6] = (bf16_t)b1.z; ko[7] = (bf16_t)b1.w;
    *(bf16x8*)(qb + (size_t)key * ATTN_D + j * 8) = qo;
    *(bf16x8*)(kswz + (size_t)key * ATTN_D + ((j ^ (key & 15)) * 8)) = ko;
  }

  {
    const float* src = v + (size_t)key * ATTN_D + bd * 64 + (t & 3) * 16;
#pragma unroll
    for (int u = 0; u < 4; ++u) {
      float4 a = ((const float4*)src)[u];
      tile[row_l][(t & 3) * 16 + u * 4 + 0] = (bf16_t)a.x;
      tile[row_l][(t & 3) * 16 + u * 4 + 1] = (bf16_t)a.y;
      tile[row_l][(t & 3) * 16 + u * 4 + 2] = (bf16_t)a.z;
      tile[row_l][(t & 3) * 16 + u * 4 + 3] = (bf16_t)a.w;
    }
  }
  __syncthreads();
  {
    const int d_l = t >> 2;            // 0..63
    const int d = bd * 64 + d_l;
    const int cq = t & 3;              // chunk 0..3 (key-slots 8cq..8cq+7)
#pragma unroll
    for (int h = 0; h < 2; ++h) {      // two 32-key v-tiles in this block
      bf16x8 o;
#pragma unroll
      for (int j = 0; j < 8; ++j) {
        // slot 8cq+j -> phys key: quad-block interleave for swapped-QK P.
        const int kl_ = h * 32 + ((j & 4) << 2) + 4 * cq + (j & 3);
        o[j] = tile[kl_][d_l];
      }
      *(bf16x8*)(vtswz + (size_t)(2 * bk + h) * TILE_ELEMS + d * TKEYS +
                 ((cq ^ ((d >> 1) & 3)) * 8)) = o;
    }
  }
}

// --- per-tile compute pieces (macros so A/B interleave is explicit) --------
#define QK_TILE(Kb, S)                                                        \
  __builtin_amdgcn_s_setprio(1);                                              \
  _Pragma("unroll")                                                           \
  for (int c = 0; c < 4; ++c) {                                               \
    bf16x8 k0_ = *(const bf16x8*)((Kb) + offK[c][0]);                         \
    bf16x8 k1_ = *(const bf16x8*)((Kb) + offK[c][1]);                         \
    S[0][0] = __builtin_amdgcn_mfma_f32_16x16x32_bf16(k0_, aq[0][c], S[0][0], 0, 0, 0); \
    S[0][1] = __builtin_amdgcn_mfma_f32_16x16x32_bf16(k0_, aq[1][c], S[0][1], 0, 0, 0); \
    S[1][0] = __builtin_amdgcn_mfma_f32_16x16x32_bf16(k1_, aq[0][c], S[1][0], 0, 0, 0); \
    S[1][1] = __builtin_amdgcn_mfma_f32_16x16x32_bf16(k1_, aq[1][c], S[1][1], 0, 0, 0); \
  }                                                                           \
  __builtin_amdgcn_s_setprio(0);

#define SM_TILE(S, AP)                                                        \
  _Pragma("unroll")                                                           \
  for (int qs = 0; qs < 2; ++qs) {                                            \
    float pa0 = EXP2(S[0][qs][0]), pa1 = EXP2(S[0][qs][1]);                   \
    float pa2 = EXP2(S[0][qs][2]), pa3 = EXP2(S[0][qs][3]);                   \
    float pb0 = EXP2(S[1][qs][0]), pb1 = EXP2(S[1][qs][1]);                   \
    float pb2 = EXP2(S[1][qs][2]), pb3 = EXP2(S[1][qs][3]);                   \
    l_part[qs] += (pa0 + pa1 + pa2 + pa3) + (pb0 + pb1 + pb2 + pb3);          \
    AP[qs][0] = (bf16_t)pa0; AP[qs][1] = (bf16_t)pa1;                         \
    AP[qs][2] = (bf16_t)pa2; AP[qs][3] = (bf16_t)pa3;                         \
    AP[qs][4] = (bf16_t)pb0; AP[qs][5] = (bf16_t)pb1;                         \
    AP[qs][6] = (bf16_t)pb2; AP[qs][7] = (bf16_t)pb3;                         \
  }

#define PV_TILE(Vb, AP)                                                       \
  __builtin_amdgcn_s_setprio(1);                                              \
  _Pragma("unroll")                                                           \
  for (int ds = 0; ds < 8; ++ds) {                                            \
    bf16x8 bv_ = *(const bf16x8*)((Vb) + offV[ds]);                           \
    oacc[0][ds] = __builtin_amdgcn_mfma_f32_16x16x32_bf16(AP[0], bv_, oacc[0][ds], 0, 0, 0); \
    oacc[1][ds] = __builtin_amdgcn_mfma_f32_16x16x32_bf16(AP[1], bv_, oacc[1][ds], 0, 0, 0); \
  }                                                                           \
  __builtin_amdgcn_s_setprio(0);

#define ISSUE_TILE(itx)                                                       \
  {                                                                           \
    const int nt_ = ktbase + ((stg + (itx)) & (KTPB - 1));                    \
    const int nb_ = (itx) & (NBUF - 1);                                       \
    _Pragma("unroll")                                                         \
    for (int u = 0; u < 2; ++u) {                                             \
      dma16(kswz + (size_t)nt_ * TILE_ELEMS + t * 8 + u * 2048,               \
            &KV[nb_][0][t * 8 + u * 2048]);                                   \
      dma16(vtswz + (size_t)nt_ * TILE_ELEMS + t * 8 + u * 2048,              \
            &KV[nb_][1][t * 8 + u * 2048]);                                   \
    }                                                                         \
  }

// ---------------------------------------------------------------------------
// Flash attention, 128 queries/block x 8-way split-K, swapped-QK register
// softmax, PERIOD-2 pipelined ring (R6 post-mortem: no pipe >50%; iteration
// period pinned by the per-tile serial chain QK->exp2->PV exposed at every
// barrier. Fix: barrier period = 2 tiles; tiles A,B computed back-to-back
// with NO barrier between -> scheduler interleaves B's QK/LDS with A's
// exp2/PV, traversing the latency chain once per 2 tiles.)
//   Period: { vmcnt(8); barrier; QK(A); QK(B); SM(A); PV(A); SM(B); PV(B);
//             barrier; issue DMA tiles A+4,B+4 }  -- 1 barrier/tile (same
//   as R6), vmcnt waits halved, never drain to 0 until tail (T4).
//   Hazards: issue-after-barrier writes bufs A&3,B&3 whose readers all
//   passed that barrier; top vmcnt(8) leaves only the next pair's 8 DMAs
//   in flight (each wave waits its OWN dmas, then barrier => all slices
//   landed, m201 pattern).
// MFMA layouts (mfma_f32_16x16x32_bf16, verified gfx950):
//   A: m = lane&15, k = (lane>>4)*8 + j
//   B: n = lane&15, k = (lane>>4)*8 + j
//   C/D: n = lane&15 (col), m = (lane>>4)*4 + reg
// ---------------------------------------------------------------------------
__global__ __launch_bounds__(256, 2) void flash_attn_kernel(
    const bf16_t* __restrict__ qb, const bf16_t* __restrict__ kswz,
    const bf16_t* __restrict__ vtswz, float* __restrict__ partO,
    float* __restrict__ partL) {
  __shared__ __align__(16) bf16_t KV[NBUF][2][TILE_ELEMS];  // 64 KB ring

  const int t = threadIdx.x;
  const int w = t >> 6;          // 0..3 = 32-row q subtile
  const int lane = t & 63;
  const int quad = lane >> 4;
  const int col = lane & 15;
  const int blk = blockIdx.x;
  const int qg = blk >> 3;       // 0..63
  const int kh = blk & 7;        // key eighth == XCD
  const int q0 = qg * QROWS;
  const int ktbase = kh * KTPB;
  const int stg = ((blk >> 3) & 3) * 8;   // stagger: decorrelate L2 streams

  // Swizzled LDS offsets (row*stride + (chunk^swz)*8).
  int offK[4][2], offV[8];
#pragma unroll
  for (int c = 0; c < 4; ++c)
#pragma unroll
    for (int ks = 0; ks < 2; ++ks)
      offK[c][ks] = (ks * 16 + col) * ATTN_D + (((c * 4 + quad) ^ col) * 8);
#pragma unroll
  for (int ds = 0; ds < 8; ++ds)
    offV[ds] = (ds * 16 + col) * TKEYS + ((quad ^ ((col >> 1) & 3)) * 8);

  // Q fragments (B operand): 2 q-subtiles x 4 k-chunks, in regs all kernel.
  bf16x8 aq[2][4];
#pragma unroll
  for (int qs = 0; qs < 2; ++qs) {
    const int row = q0 + w * 32 + qs * 16 + col;
#pragma unroll
    for (int c = 0; c < 4; ++c)
      aq[qs][c] = *(const bf16x8*)(qb + (size_t)row * ATTN_D + c * 32 + quad * 8);
  }

  f32x4 oacc[2][8];
#pragma unroll
  for (int qs = 0; qs < 2; ++qs)
#pragma unroll
    for (int i = 0; i < 8; ++i) oacc[qs][i] = (f32x4){0.f, 0.f, 0.f, 0.f};
  float l_part[2] = {0.f, 0.f};

  // Prologue: tiles 0..3 into the 4 ring bufs (16 dma16/thread outstanding).
#pragma unroll
  for (int pt = 0; pt < NBUF; ++pt) ISSUE_TILE(pt);

  for (int p2 = 0; p2 < KTPB; p2 += 2) {
    const int bA = p2 & (NBUF - 1);
    const int bB = (p2 + 1) & (NBUF - 1);
    // Tiles p2,p2+1 landed (their 8 dmas are the oldest); next pair stays
    // in flight. Tail: nothing newer outstanding -> drain.
    if (p2 + 2 < KTPB)
      asm volatile("s_waitcnt vmcnt(8)" ::: "memory");
    else
      asm volatile("s_waitcnt vmcnt(0)" ::: "memory");
    __builtin_amdgcn_s_barrier();

    const bf16_t* KbA = KV[bA][0];
    const bf16_t* VbA = KV[bA][1];
    const bf16_t* KbB = KV[bB][0];
    const bf16_t* VbB = KV[bB][1];

    f32x4 sA[2][2], sB[2][2];
#pragma unroll
    for (int ks = 0; ks < 2; ++ks)
#pragma unroll
      for (int qs = 0; qs < 2; ++qs) {
        sA[ks][qs] = (f32x4){0.f, 0.f, 0.f, 0.f};
        sB[ks][qs] = (f32x4){0.f, 0.f, 0.f, 0.f};
      }

    bf16x8 apA[2], apB[2];
    // Interleaved 2-tile schedule: B's QK fills A's exp2/PV latency; A's PV
    // MFMAs (matrix pipe) overlap B's softmax (VALU pipe).
    QK_TILE(KbA, sA)
    QK_TILE(KbB, sB)
    SM_TILE(sA, apA)
    PV_TILE(VbA, apA)
    SM_TILE(sB, apB)
    PV_TILE(VbB, apB)

    // All waves done reading bufs bA,bB -> safe to refill them.
    if (p2 + 4 < KTPB) {
      __builtin_amdgcn_s_barrier();
      ISSUE_TILE(p2 + 4);
      ISSUE_TILE(p2 + 5);
    }
  }

  // --- epilogue: partial L. Lane holds the sum over its 8 keys for q=col;
  //     total over the 32-key tiles = reduce across the 4 quads.
#pragma unroll
  for (int qs = 0; qs < 2; ++qs) {
    float v = l_part[qs];
    v += __shfl_xor(v, 16, 64);
    v += __shfl_xor(v, 32, 64);
    if (quad == 0)
      partL[(size_t)blk * QROWS + w * 32 + qs * 16 + col] = v;
  }

  // --- direct store of this wave's 32 unnormalized O rows.
  {
    float* dst = partO + ((size_t)blk * QROWS + w * 32) * ATTN_D;
#pragma unroll
    for (int qs = 0; qs < 2; ++qs)
#pragma unroll
      for (int ds = 0; ds < 8; ++ds)
#pragma unroll
        for (int r = 0; r < 4; ++r)
          dst[(qs * 16 + quad * 4 + r) * ATTN_D + ds * 16 + col] = oacc[qs][ds][r];
  }
}

// ---------------------------------------------------------------------------
// Merge: out[row] = (sum of 8 split-K partial O) / (sum of 8 partial L).
//   1024 blocks x 256 threads, one float4 per thread.
// ---------------------------------------------------------------------------
__global__ void merge_kernel(const float* __restrict__ partO,
                             const float* __restrict__ partL,
                             float* __restrict__ out) {
  const int idx = blockIdx.x * blockDim.x + threadIdx.x;  // float4 index
  const int row = idx >> 5;          // 32 float4 per 128-elem row
  const int gi = row >> 7;           // query group 0..63
  const int rl = row & 127;
  const int li = rl * 32 + (idx & 31);
  float L = 0.f;
  float4 acc = {0.f, 0.f, 0.f, 0.f};
#pragma unroll
  for (int i = 0; i < 8; ++i) {
    const size_t b = (size_t)(8 * gi + i);
    L += partL[b * QROWS + rl];
    float4 a = ((const float4*)(partO + b * (QROWS * ATTN_D)))[li];
    acc.x += a.x; acc.y += a.y; acc.z += a.z; acc.w += a.w;
  }
  const float invL = 1.0f / L;
  float4 o;
  o.x = acc.x * invL; o.y = acc.y * invL;
  o.z = acc.z * invL; o.w = acc.w * invL;
  ((float4*)out)[idx] = o;
}

// ---------------------------------------------------------------------------
extern "C" void kernel_launch(void* const* d_in, const int* in_sizes, int n_in,
                              void* d_out, int out_size, void* d_ws, size_t ws_size,
                              hipStream_t stream) {
  const float* q = (const float*)d_in[0];
  const float* k = (const float*)d_in[1];
  const float* v = (const float*)d_in[2];
  float* out = (float*)d_out;

  // Workspace: qb | kswz | vtswz (bf16, 2 MB each) | partO 33.6 MB | partL 256 KB.
  bf16_t* qb = (bf16_t*)d_ws;
  bf16_t* kswz = qb + (size_t)ATTN_N * ATTN_D;
  bf16_t* vtswz = kswz + (size_t)ATTN_N * ATTN_D;
  float* partO = (float*)(vtswz + (size_t)ATTN_N * ATTN_D);
  float* partL = partO + (size_t)512 * QROWS * ATTN_D;

  prep_kernel<<<dim3(ATTN_N / 64, 2), 256, 0, stream>>>(q, k, v, qb, kswz, vtswz);
  flash_attn_kernel<<<512, 256, 0, stream>>>(qb, kswz, vtswz, partO, partL);
  merge_kernel<<<(ATTN_N * ATTN_D / 4) / 256, 256, 0, stream>>>(partO, partL, out);
}